// Round 5
// baseline (1174.119 us; speedup 1.0000x reference)
//
#include <hip/hip_runtime.h>

#define E 1024
#define H 4096
#define NLAYER 24
#define V 50277
#define NB 256
#define NT 1024
#define NWAVE ((NB * NT) / 64)   // 4096 waves
#define LN_EPS 1e-5f

struct Params {
  const float* emb;   const float* ln0_w; const float* ln0_b;
  const float* ln1_w; const float* ln1_b;
  const float* tmk;   const float* tmv;   const float* tmr;
  const float* tf;    const float* td;
  const float* kw;    const float* vw;    const float* rw;  const float* ow;
  const float* ln2_w; const float* ln2_b;
  const float* ftmk;  const float* ftmr;
  const float* fkw;   const float* fvw;   const float* frw;
  const float* lnow;  const float* lnob;  const float* headw;
  const float* st;    const int* tok;
  float* out; float* ws;
};

// ---- agent-scope (device-coherent, cache-bypassing) load/store helpers ----
__device__ __forceinline__ void stg(float* p, float v) {
  __hip_atomic_store(p, v, __ATOMIC_RELAXED, __HIP_MEMORY_SCOPE_AGENT);
}
__device__ __forceinline__ float ldg1(const float* p) {
  return __hip_atomic_load(p, __ATOMIC_RELAXED, __HIP_MEMORY_SCOPE_AGENT);
}

// every wave: ensure its sc1 data stores are acked at the coherence point.
// MUST be called before issuing prefetch loads (so they aren't drained too).
__device__ __forceinline__ void drain_stores() {
  asm volatile("s_waitcnt vmcnt(0) lgkmcnt(0)" ::: "memory");
}

// single-counter relaxed grid barrier; fire-and-forget arrive, thread-0 spin.
// Counter zeroed by hipMemsetAsync before each launch; monotonic targets.
__device__ __forceinline__ void gbar(unsigned* cnt, unsigned target) {
  __syncthreads();
  if (threadIdx.x == 0) {
    __hip_atomic_fetch_add(cnt, 1u, __ATOMIC_RELAXED, __HIP_MEMORY_SCOPE_AGENT);
    while (__hip_atomic_load(cnt, __ATOMIC_RELAXED, __HIP_MEMORY_SCOPE_AGENT) < target)
      __builtin_amdgcn_s_sleep(1);
  }
  __syncthreads();
}

__device__ __forceinline__ float warp_sum(float v) {
#pragma unroll
  for (int off = 32; off; off >>= 1) v += __shfl_down(v, off);
  return v;
}

__device__ float block_sum(float v, float* red) {
  v = warp_sum(v);
  const int wid = threadIdx.x >> 6, lane = threadIdx.x & 63;
  if (lane == 0) red[wid] = v;
  __syncthreads();
  float s = (threadIdx.x < 16) ? red[threadIdx.x] : 0.f;
  if (wid == 0) {
#pragma unroll
    for (int off = 8; off; off >>= 1) s += __shfl_down(s, off);
    if (lane == 0) red[0] = s;
  }
  __syncthreads();
  float r = red[0];
  __syncthreads();
  return r;
}

__device__ __forceinline__ float dot4(float4 a, float4 b) {
  return a.x * b.x + a.y * b.y + a.z * b.z + a.w * b.w;
}

// K=1024 dot with in-register weights (4x float4), vector from LDS
__device__ __forceinline__ float dotreg(float4 w0, float4 w1, float4 w2, float4 w3,
                                        const float* vec, int lane) {
  const float4* v4 = (const float4*)vec;
  float acc = dot4(w0, v4[lane]) + dot4(w1, v4[lane + 64]) +
              dot4(w2, v4[lane + 128]) + dot4(w3, v4[lane + 192]);
  return warp_sum(acc);
}

// plain streaming K=1024 dot (head)
__device__ __forceinline__ float dot1024(const float* __restrict__ Wrow,
                                         const float* vec, int lane) {
  const float4* W4 = (const float4*)Wrow;
  const float4* v4 = (const float4*)vec;
  float acc = 0.f;
#pragma unroll
  for (int p = 0; p < 4; ++p) {
    float4 w = W4[lane + p * 64];
    float4 x = v4[lane + p * 64];
    acc += dot4(w, x);
  }
  return warp_sum(acc);
}

__global__ __launch_bounds__(NT, 4) void rwkv_kernel(Params p) {
  const int tid = threadIdx.x, bid = blockIdx.x;
  const int lane = tid & 63, wid = tid >> 6;
  const int gw = bid * (NT / 64) + wid;   // global wave id, 0..4095

  __shared__ __align__(16) float s_x[E];
  __shared__ __align__(16) float s_xk[E];
  __shared__ __align__(16) float s_xv[E];
  __shared__ __align__(16) float s_xr[E];
  __shared__ __align__(16) float s_wkv[E];
  __shared__ __align__(16) float s_sx[E];
  __shared__ __align__(16) float s_fxk[E];
  __shared__ __align__(16) float s_fxr[E];
  __shared__ __align__(16) float s_fk[H];
  __shared__ float s_red[16];
  __shared__ float s_part[16];

  unsigned* bar = (unsigned*)p.ws;
  float* wsd  = p.ws + 4096;
  float* ws_x  = wsd;
  float* ws_k  = wsd + E;
  float* ws_v  = wsd + 2 * E;
  float* ws_r  = wsd + 3 * E;
  float* ws_sx = wsd + 4 * E;
  float* ws_fr = wsd + 5 * E;
  float* ws_fk = wsd + 6 * E;          // H floats

  unsigned gen = 0;
  float* out_st = p.out + V;
  const int token = p.tok[0];

  // wave->row mapping (constant across layers)
  const bool hasA = gw < 3 * E;
  const int matA = gw >> 10, rmA = gw & (E - 1);
  const int rlocB = wid >> 2, kcB = wid & 3, rowB = bid * 4 + rlocB;
  const bool hasF = gw < E;             // frw row
  const int rlocD = wid >> 2, kcD = wid & 3, rowD = bid * 4 + rlocD;

  // ---- prefetch phase A (l=0) weights + params, overlaps LN0 ----
  float4 pa0, pa1, pa2, pa3;
  if (hasA) {
    const float* W = (matA == 0 ? p.kw : matA == 1 ? p.vw : p.rw) + (size_t)rmA * E;
    const float4* W4 = (const float4*)W;
    pa0 = W4[lane]; pa1 = W4[lane + 64]; pa2 = W4[lane + 128]; pa3 = W4[lane + 192];
  }
  float ln1w = p.ln1_w[tid], ln1b = p.ln1_b[tid];
  float tmk_ = p.tmk[tid], tmv_ = p.tmv[tid], tmr_ = p.tmr[tid];
  float attx = p.st[1 * E + tid];

  // x = LN0(emb[token])
  {
    float v = p.emb[(size_t)token * E + tid];
    float m = block_sum(v, s_red) * (1.f / E);
    float d = v - m;
    float var = block_sum(d * d, s_red) * (1.f / E);
    s_x[tid] = d / sqrtf(var + LN_EPS) * p.ln0_w[tid] + p.ln0_b[tid];
  }
  __syncthreads();

  for (int l = 0; l < NLAYER; ++l) {
    const float* stl = p.st + (size_t)5 * l * E;
    float* ostl = out_st + (size_t)5 * l * E;

    // ================ Phase A: LN1 + mix + k/v/r matvecs ================
    {
      float xv_ = s_x[tid];
      float m = block_sum(xv_, s_red) * (1.f / E);
      float d = xv_ - m;
      float var = block_sum(d * d, s_red) * (1.f / E);
      float xn = d / sqrtf(var + LN_EPS) * ln1w + ln1b;
      s_xk[tid] = xn * tmk_ + attx * (1.f - tmk_);
      s_xv[tid] = xn * tmv_ + attx * (1.f - tmv_);
      s_xr[tid] = xn * tmr_ + attx * (1.f - tmr_);
      if (bid == 0) ostl[1 * E + tid] = xn;       // new att_x
    }
    __syncthreads();
    if (hasA) {
      const float* vec = (matA == 0) ? s_xk : (matA == 1) ? s_xv : s_xr;
      float dres = dotreg(pa0, pa1, pa2, pa3, vec, lane);
      if (lane == 0) {
        if (matA == 0)      stg(&ws_k[rmA], dres);
        else if (matA == 1) stg(&ws_v[rmA], dres);
        else                stg(&ws_r[rmA], 1.f / (1.f + expf(-dres)));
      }
    }
    drain_stores();
    // prefetch phase B: ow row segment + wkv params
    float4 pb = ((const float4*)(p.ow + (size_t)l * E * E + (size_t)rowB * E + kcB * 256))[lane];
    float aav = stl[2 * E + tid], bbv = stl[3 * E + tid], ppv = stl[4 * E + tid];
    float tfv = p.tf[l * E + tid], tdv = p.td[l * E + tid];
    gbar(bar, ++gen * NB);

    // ================ Phase B: WKV + ow matvec ================
    {
      float kk = ldg1(&ws_k[tid]), vv = ldg1(&ws_v[tid]), rr = ldg1(&ws_r[tid]);
      float wwv = tfv + kk;
      float pm = fmaxf(ppv, wwv);
      float e1 = expf(ppv - pm), e2 = expf(wwv - pm);
      float a = e1 * aav + e2 * vv, b = e1 * bbv + e2;
      s_wkv[tid] = rr * a / b;
      float ww2 = ppv + tdv;
      float p2 = fmaxf(ww2, kk);
      float f1 = expf(ww2 - p2), f2 = expf(kk - p2);
      if (bid == 0) {
        ostl[2 * E + tid] = f1 * aav + f2 * vv;    // naa
        ostl[3 * E + tid] = f1 * bbv + f2;         // nbb
        ostl[4 * E + tid] = p2;                    // npp
      }
    }
    __syncthreads();
    {
      const float4* v4 = (const float4*)(s_wkv + kcB * 256);
      float acc = warp_sum(dot4(pb, v4[lane]));
      if (lane == 0) s_part[wid] = acc;
      __syncthreads();
      if (tid < 4) {
        int r2 = bid * 4 + tid;
        float dsum = s_part[tid * 4] + s_part[tid * 4 + 1] +
                     s_part[tid * 4 + 2] + s_part[tid * 4 + 3];
        stg(&ws_sx[r2], s_x[r2] + dsum);
      }
    }
    drain_stores();
    // prefetch phase C: fkw row (all waves) + frw row (gw<E) + params
    float4 pc0, pc1, pc2, pc3, pf0, pf1, pf2, pf3;
    {
      const float4* W4 = (const float4*)(p.fkw + (size_t)l * H * E + (size_t)gw * E);
      pc0 = W4[lane]; pc1 = W4[lane + 64]; pc2 = W4[lane + 128]; pc3 = W4[lane + 192];
      if (hasF) {
        const float4* F4 = (const float4*)(p.frw + (size_t)l * E * E + (size_t)gw * E);
        pf0 = F4[lane]; pf1 = F4[lane + 64]; pf2 = F4[lane + 128]; pf3 = F4[lane + 192];
      }
    }
    float ln2w = p.ln2_w[l * E + tid], ln2b = p.ln2_b[l * E + tid];
    float ftk = p.ftmk[l * E + tid], ftr = p.ftmr[l * E + tid];
    float ffnx = stl[0 * E + tid];
    gbar(bar, ++gen * NB);

    // ================ Phase C: LN2 + mix + fkw/frw matvecs ================
    {
      float sxv = ldg1(&ws_sx[tid]);
      s_sx[tid] = sxv;
      float m = block_sum(sxv, s_red) * (1.f / E);
      float d = sxv - m;
      float var = block_sum(d * d, s_red) * (1.f / E);
      float xn2 = d / sqrtf(var + LN_EPS) * ln2w + ln2b;
      s_fxk[tid] = xn2 * ftk + ffnx * (1.f - ftk);
      s_fxr[tid] = xn2 * ftr + ffnx * (1.f - ftr);
      if (bid == 0) ostl[0 * E + tid] = xn2;       // new ffn_x
    }
    __syncthreads();
    {
      float dres = dotreg(pc0, pc1, pc2, pc3, s_fxk, lane);
      if (lane == 0) { float t = fmaxf(dres, 0.f); stg(&ws_fk[gw], t * t); }
      if (hasF) {
        float dr2 = dotreg(pf0, pf1, pf2, pf3, s_fxr, lane);
        if (lane == 0) stg(&ws_fr[gw], 1.f / (1.f + expf(-dr2)));
      }
    }
    drain_stores();
    // prefetch phase D: fvw row segment
    float4 pd0, pd1, pd2, pd3;
    {
      const float4* W4 = (const float4*)(p.fvw + (size_t)l * E * H + (size_t)rowD * H + kcD * 1024);
      pd0 = W4[lane]; pd1 = W4[lane + 64]; pd2 = W4[lane + 128]; pd3 = W4[lane + 192];
    }
    gbar(bar, ++gen * NB);

    // ================ Phase D: fvw matvec + residual ================
    {
#pragma unroll
      for (int i = 0; i < 4; ++i) s_fk[tid + i * NT] = ldg1(&ws_fk[tid + i * NT]);
      __syncthreads();
      const float4* v4 = (const float4*)(s_fk + kcD * 1024);
      float acc = dot4(pd0, v4[lane]) + dot4(pd1, v4[lane + 64]) +
                  dot4(pd2, v4[lane + 128]) + dot4(pd3, v4[lane + 192]);
      acc = warp_sum(acc);
      if (lane == 0) s_part[wid] = acc;
      __syncthreads();
      if (tid < 4) {
        int r2 = bid * 4 + tid;
        float dsum = s_part[tid * 4] + s_part[tid * 4 + 1] +
                     s_part[tid * 4 + 2] + s_part[tid * 4 + 3];
        stg(&ws_x[r2], s_sx[r2] + ldg1(&ws_fr[r2]) * dsum);
      }
    }
    drain_stores();
    // prefetch phase A of next layer
    if (l + 1 < NLAYER) {
      if (hasA) {
        const float* W = (matA == 0 ? p.kw : matA == 1 ? p.vw : p.rw) +
                         (size_t)(l + 1) * E * E + (size_t)rmA * E;
        const float4* W4 = (const float4*)W;
        pa0 = W4[lane]; pa1 = W4[lane + 64]; pa2 = W4[lane + 128]; pa3 = W4[lane + 192];
      }
      ln1w = p.ln1_w[(l + 1) * E + tid]; ln1b = p.ln1_b[(l + 1) * E + tid];
      tmk_ = p.tmk[(l + 1) * E + tid];
      tmv_ = p.tmv[(l + 1) * E + tid];
      tmr_ = p.tmr[(l + 1) * E + tid];
      attx = p.st[(size_t)5 * (l + 1) * E + 1 * E + tid];
    }
    gbar(bar, ++gen * NB);

    s_x[tid] = ldg1(&ws_x[tid]);
    __syncthreads();
  }

  // ================ Head: LN_out + V x E matvec ================
  {
    float xv_ = s_x[tid];
    float m = block_sum(xv_, s_red) * (1.f / E);
    float d = xv_ - m;
    float var = block_sum(d * d, s_red) * (1.f / E);
    s_xk[tid] = d / sqrtf(var + LN_EPS) * p.lnow[tid] + p.lnob[tid];
  }
  __syncthreads();
  for (int row = gw; row < V; row += NWAVE) {
    const float* Wr = p.headw + (size_t)row * E;
    float dres = dot1024(Wr, s_xk, lane);
    if (lane == 0) p.out[row] = dres;
  }
}

extern "C" void kernel_launch(void* const* d_in, const int* in_sizes, int n_in,
                              void* d_out, int out_size, void* d_ws, size_t ws_size,
                              hipStream_t stream) {
  Params p;
  p.emb   = (const float*)d_in[0];
  p.ln0_w = (const float*)d_in[1];
  p.ln0_b = (const float*)d_in[2];
  p.ln1_w = (const float*)d_in[3];
  p.ln1_b = (const float*)d_in[4];
  p.tmk   = (const float*)d_in[5];
  p.tmv   = (const float*)d_in[6];
  p.tmr   = (const float*)d_in[7];
  p.tf    = (const float*)d_in[8];
  p.td    = (const float*)d_in[9];
  p.kw    = (const float*)d_in[10];
  p.vw    = (const float*)d_in[11];
  p.rw    = (const float*)d_in[12];
  p.ow    = (const float*)d_in[13];
  p.ln2_w = (const float*)d_in[14];
  p.ln2_b = (const float*)d_in[15];
  p.ftmk  = (const float*)d_in[16];
  p.ftmr  = (const float*)d_in[17];
  p.fkw   = (const float*)d_in[18];
  p.fvw   = (const float*)d_in[19];
  p.frw   = (const float*)d_in[20];
  p.lnow  = (const float*)d_in[21];
  p.lnob  = (const float*)d_in[22];
  p.headw = (const float*)d_in[23];
  if (in_sizes[24] == 1) {
    p.tok = (const int*)d_in[24];
    p.st  = (const float*)d_in[25];
  } else {
    p.st  = (const float*)d_in[24];
    p.tok = (const int*)d_in[25];
  }
  p.out   = (float*)d_out;
  p.ws    = (float*)d_ws;

  // zero the barrier counter region deterministically every call (graph node)
  hipMemsetAsync(d_ws, 0, 16384, stream);

  void* args[] = { &p };
  hipLaunchCooperativeKernel((const void*)rwkv_kernel, dim3(NB), dim3(NT),
                             args, 0, stream);
}

// Round 6
// 1110.519 us; speedup vs baseline: 1.0573x; 1.0573x over previous
//
#include <hip/hip_runtime.h>

#define E 1024
#define H 4096
#define NLAYER 24
#define V 50277
#define NB 256
#define NT 1024
#define NWAVE ((NB * NT) / 64)   // 4096 waves
#define LN_EPS 1e-5f

// LDS float offsets (dynamic shared)
#define WBUF 0            // 24576 floats (96 KB) weight prefetch buffer
#define OFF_X    24576
#define OFF_XK   25600
#define OFF_XV   26624
#define OFF_XR   27648
#define OFF_WKV  28672
#define OFF_SX   29696
#define OFF_FXK  30720
#define OFF_FXR  31744
#define OFF_FK   32768    // 4096 floats
#define OFF_RED  36864    // 16
#define OFF_PART 36880    // 16
#define SMEM_FLOATS 36896

struct Params {
  const float* emb;   const float* ln0_w; const float* ln0_b;
  const float* ln1_w; const float* ln1_b;
  const float* tmk;   const float* tmv;   const float* tmr;
  const float* tf;    const float* td;
  const float* kw;    const float* vw;    const float* rw;  const float* ow;
  const float* ln2_w; const float* ln2_b;
  const float* ftmk;  const float* ftmr;
  const float* fkw;   const float* fvw;   const float* frw;
  const float* lnow;  const float* lnob;  const float* headw;
  const float* st;    const int* tok;
  float* out; float* ws;
};

// ---- agent-scope (device-coherent, cache-bypassing) load/store helpers ----
__device__ __forceinline__ void stg(float* p, float v) {
  __hip_atomic_store(p, v, __ATOMIC_RELAXED, __HIP_MEMORY_SCOPE_AGENT);
}
__device__ __forceinline__ float ldg1(const float* p) {
  return __hip_atomic_load(p, __ATOMIC_RELAXED, __HIP_MEMORY_SCOPE_AGENT);
}

// drain this wave's outstanding vmem (data stores) before barrier arrive.
// MUST be called BEFORE issuing prefetch loads.
__device__ __forceinline__ void drain_vm() {
  asm volatile("s_waitcnt vmcnt(0) lgkmcnt(0)" ::: "memory");
}
// wait for this wave's prefetch (global_load_lds) to land in LDS
__device__ __forceinline__ void wait_pf() {
  asm volatile("s_waitcnt vmcnt(0)" ::: "memory");
}

// zero-VGPR global->LDS DMA: 64 lanes x 16 B = 1 KB per call.
// g: per-lane global addr (lane i reads g[lane*4 .. +4)); l: wave-uniform LDS base.
__device__ __forceinline__ void gload_lds16(const float* g, float* l) {
  __builtin_amdgcn_global_load_lds(
      (const __attribute__((address_space(1))) unsigned int*)(g),
      (__attribute__((address_space(3))) unsigned int*)(l), 16, 0, 0);
}
// prefetch a full 4 KB row (1024 floats)
__device__ __forceinline__ void pf_row4k(const float* row, float* dst, int lane) {
#pragma unroll
  for (int c = 0; c < 4; ++c)
    gload_lds16(row + c * 256 + lane * 4, dst + c * 256);
}

// single-counter relaxed grid barrier; fire-and-forget arrive, thread-0 spin.
// Counter zeroed by hipMemsetAsync before each launch; monotonic targets.
__device__ __forceinline__ void gbar(unsigned* cnt, unsigned target) {
  __syncthreads();
  if (threadIdx.x == 0) {
    __hip_atomic_fetch_add(cnt, 1u, __ATOMIC_RELAXED, __HIP_MEMORY_SCOPE_AGENT);
    while (__hip_atomic_load(cnt, __ATOMIC_RELAXED, __HIP_MEMORY_SCOPE_AGENT) < target)
      __builtin_amdgcn_s_sleep(1);
  }
  __syncthreads();
}

__device__ __forceinline__ float warp_sum(float v) {
#pragma unroll
  for (int off = 32; off; off >>= 1) v += __shfl_down(v, off);
  return v;
}

__device__ float block_sum(float v, float* red) {
  v = warp_sum(v);
  const int wid = threadIdx.x >> 6, lane = threadIdx.x & 63;
  if (lane == 0) red[wid] = v;
  __syncthreads();
  float s = (threadIdx.x < 16) ? red[threadIdx.x] : 0.f;
  if (wid == 0) {
#pragma unroll
    for (int off = 8; off; off >>= 1) s += __shfl_down(s, off);
    if (lane == 0) red[0] = s;
  }
  __syncthreads();
  float r = red[0];
  __syncthreads();
  return r;
}

__device__ __forceinline__ float dot4(float4 a, float4 b) {
  return a.x * b.x + a.y * b.y + a.z * b.z + a.w * b.w;
}

// K=1024 dot, weights from LDS (wave-private prefetched row), vec from LDS
__device__ __forceinline__ float dotlds(const float* wrow, const float* vec, int lane) {
  const float4* w4 = (const float4*)wrow;
  const float4* v4 = (const float4*)vec;
  float acc = 0.f;
#pragma unroll
  for (int p = 0; p < 4; ++p)
    acc += dot4(w4[lane + p * 64], v4[lane + p * 64]);
  return warp_sum(acc);
}

// plain streaming K=1024 dot (head)
__device__ __forceinline__ float dot1024(const float* __restrict__ Wrow,
                                         const float* vec, int lane) {
  const float4* W4 = (const float4*)Wrow;
  const float4* v4 = (const float4*)vec;
  float acc = 0.f;
#pragma unroll
  for (int p = 0; p < 4; ++p)
    acc += dot4(W4[lane + p * 64], v4[lane + p * 64]);
  return warp_sum(acc);
}

__global__ __launch_bounds__(NT, 1) void rwkv_kernel(Params p) {
  const int tid = threadIdx.x, bid = blockIdx.x;
  const int lane = tid & 63, wid = tid >> 6;
  const int gw = bid * (NT / 64) + wid;   // global wave id, 0..4095

  extern __shared__ float smem[];
  float* wbuf  = smem + WBUF;
  float* s_x   = smem + OFF_X;
  float* s_xk  = smem + OFF_XK;
  float* s_xv  = smem + OFF_XV;
  float* s_xr  = smem + OFF_XR;
  float* s_wkv = smem + OFF_WKV;
  float* s_sx  = smem + OFF_SX;
  float* s_fxk = smem + OFF_FXK;
  float* s_fxr = smem + OFF_FXR;
  float* s_fk  = smem + OFF_FK;
  float* s_red = smem + OFF_RED;
  float* s_part= smem + OFF_PART;

  unsigned* bar = (unsigned*)p.ws;
  float* wsd  = p.ws + 4096;
  float* ws_x  = wsd;
  float* ws_k  = wsd + E;
  float* ws_v  = wsd + 2 * E;
  float* ws_r  = wsd + 3 * E;
  float* ws_sx = wsd + 4 * E;
  float* ws_fr = wsd + 5 * E;
  float* ws_fk = wsd + 6 * E;          // H floats

  unsigned gen = 0;
  float* out_st = p.out + V;
  const int token = p.tok[0];

  // wave->row mapping (constant across layers)
  const bool hasA = gw < 3 * E;                     // k/v/r rows
  const int matA = gw >> 10, rmA = gw & (E - 1);
  const int rlocB = wid >> 2, kcB = wid & 3, rowB = bid * 4 + rlocB;
  const int rlocD = wid >> 2, kcD = wid & 3, rowD = bid * 4 + rlocD;
  // LDS weight regions (floats): A/C-fkw/D at wbuf+wid*1024 [0,16K);
  // B at wbuf+16384+wid*256 [16K,20K); C-frw at wbuf+20480+wid*1024 [20K,24K)
  float* wA = wbuf + wid * 1024;
  float* wB = wbuf + 16384 + wid * 256;
  float* wF = wbuf + 20480 + wid * 1024;

  // ---- prefetch phase A (l=0) weights into LDS, overlaps LN0 ----
  if (hasA) {
    const float* W = (matA == 0 ? p.kw : matA == 1 ? p.vw : p.rw) + (size_t)rmA * E;
    pf_row4k(W, wA, lane);
  }
  float ln1w = p.ln1_w[tid], ln1b = p.ln1_b[tid];
  float tmk_ = p.tmk[tid], tmv_ = p.tmv[tid], tmr_ = p.tmr[tid];
  float attx = p.st[1 * E + tid];

  // x = LN0(emb[token])
  {
    float v = p.emb[(size_t)token * E + tid];
    float m = block_sum(v, s_red) * (1.f / E);
    float d = v - m;
    float var = block_sum(d * d, s_red) * (1.f / E);
    s_x[tid] = d / sqrtf(var + LN_EPS) * p.ln0_w[tid] + p.ln0_b[tid];
  }
  __syncthreads();

  for (int l = 0; l < NLAYER; ++l) {
    const float* stl = p.st + (size_t)5 * l * E;
    float* ostl = out_st + (size_t)5 * l * E;

    // ================ Phase A: LN1 + mix + k/v/r matvecs ================
    {
      float xv_ = s_x[tid];
      float m = block_sum(xv_, s_red) * (1.f / E);
      float d = xv_ - m;
      float var = block_sum(d * d, s_red) * (1.f / E);
      float xn = d / sqrtf(var + LN_EPS) * ln1w + ln1b;
      s_xk[tid] = xn * tmk_ + attx * (1.f - tmk_);
      s_xv[tid] = xn * tmv_ + attx * (1.f - tmv_);
      s_xr[tid] = xn * tmr_ + attx * (1.f - tmr_);
      if (bid == 0) ostl[1 * E + tid] = xn;       // new att_x
    }
    wait_pf();          // A weights landed (wave-private region)
    __syncthreads();
    if (hasA) {
      const float* vec = (matA == 0) ? s_xk : (matA == 1) ? s_xv : s_xr;
      float dres = dotlds(wA, vec, lane);
      if (lane == 0) {
        if (matA == 0)      stg(&ws_k[rmA], dres);
        else if (matA == 1) stg(&ws_v[rmA], dres);
        else                stg(&ws_r[rmA], 1.f / (1.f + expf(-dres)));
      }
    }
    drain_vm();
    // prefetch B weights (ow row chunk, 1 KB) into disjoint region
    gload_lds16(p.ow + (size_t)l * E * E + (size_t)rowB * E + kcB * 256 + lane * 4, wB);
    // B params into registers
    float aav = stl[2 * E + tid], bbv = stl[3 * E + tid], ppv = stl[4 * E + tid];
    float tfv = p.tf[l * E + tid], tdv = p.td[l * E + tid];
    gbar(bar, ++gen * NB);

    // ================ Phase B: WKV + ow matvec ================
    {
      float kk = ldg1(&ws_k[tid]), vv = ldg1(&ws_v[tid]), rr = ldg1(&ws_r[tid]);
      float wwv = tfv + kk;
      float pm = fmaxf(ppv, wwv);
      float e1 = expf(ppv - pm), e2 = expf(wwv - pm);
      float a = e1 * aav + e2 * vv, b = e1 * bbv + e2;
      s_wkv[tid] = rr * a / b;
      float ww2 = ppv + tdv;
      float p2 = fmaxf(ww2, kk);
      float f1 = expf(ww2 - p2), f2 = expf(kk - p2);
      if (bid == 0) {
        ostl[2 * E + tid] = f1 * aav + f2 * vv;    // naa
        ostl[3 * E + tid] = f1 * bbv + f2;         // nbb
        ostl[4 * E + tid] = p2;                    // npp
      }
    }
    wait_pf();          // B weights landed
    __syncthreads();
    {
      const float4* v4 = (const float4*)(s_wkv + kcB * 256);
      const float4* w4 = (const float4*)wB;
      float acc = warp_sum(dot4(w4[lane], v4[lane]));
      if (lane == 0) s_part[wid] = acc;
      __syncthreads();
      if (tid < 4) {
        int r2 = bid * 4 + tid;
        float dsum = s_part[tid * 4] + s_part[tid * 4 + 1] +
                     s_part[tid * 4 + 2] + s_part[tid * 4 + 3];
        stg(&ws_sx[r2], s_x[r2] + dsum);
      }
    }
    drain_vm();
    // prefetch C weights: fkw row (all waves) + frw row (wid<4)
    pf_row4k(p.fkw + (size_t)l * H * E + (size_t)gw * E, wA, lane);
    if (wid < 4)
      pf_row4k(p.frw + (size_t)l * E * E + (size_t)(bid * 4 + wid) * E, wF, lane);
    // C params
    float ln2w = p.ln2_w[l * E + tid], ln2b = p.ln2_b[l * E + tid];
    float ftk = p.ftmk[l * E + tid], ftr = p.ftmr[l * E + tid];
    float ffnx = stl[0 * E + tid];
    gbar(bar, ++gen * NB);

    // ================ Phase C: LN2 + mix + fkw/frw matvecs ================
    {
      float sxv = ldg1(&ws_sx[tid]);
      s_sx[tid] = sxv;
      float m = block_sum(sxv, s_red) * (1.f / E);
      float d = sxv - m;
      float var = block_sum(d * d, s_red) * (1.f / E);
      float xn2 = d / sqrtf(var + LN_EPS) * ln2w + ln2b;
      s_fxk[tid] = xn2 * ftk + ffnx * (1.f - ftk);
      s_fxr[tid] = xn2 * ftr + ffnx * (1.f - ftr);
      if (bid == 0) ostl[0 * E + tid] = xn2;       // new ffn_x
    }
    wait_pf();          // C weights landed
    __syncthreads();
    {
      float dres = dotlds(wA, s_fxk, lane);
      if (lane == 0) { float t = fmaxf(dres, 0.f); stg(&ws_fk[gw], t * t); }
      if (wid < 4) {
        float dr2 = dotlds(wF, s_fxr, lane);
        if (lane == 0) stg(&ws_fr[bid * 4 + wid], 1.f / (1.f + expf(-dr2)));
      }
    }
    drain_vm();
    // prefetch D weights (fvw row chunk, 4 KB) into [0,16K) (own region, consumed)
    pf_row4k(p.fvw + (size_t)l * E * H + (size_t)rowD * H + kcD * 1024, wA, lane);
    gbar(bar, ++gen * NB);

    // ================ Phase D: fvw matvec + residual ================
    {
#pragma unroll
      for (int i = 0; i < 4; ++i) s_fk[tid + i * NT] = ldg1(&ws_fk[tid + i * NT]);
      wait_pf();        // D weights landed
      __syncthreads();
      const float4* v4 = (const float4*)(s_fk + kcD * 1024);
      const float4* w4 = (const float4*)wA;
      float acc = 0.f;
#pragma unroll
      for (int pc = 0; pc < 4; ++pc)
        acc += dot4(w4[lane + pc * 64], v4[lane + pc * 64]);
      acc = warp_sum(acc);
      if (lane == 0) s_part[wid] = acc;
      __syncthreads();
      if (tid < 4) {
        int r2 = bid * 4 + tid;
        float dsum = s_part[tid * 4] + s_part[tid * 4 + 1] +
                     s_part[tid * 4 + 2] + s_part[tid * 4 + 3];
        stg(&ws_x[r2], s_sx[r2] + ldg1(&ws_fr[r2]) * dsum);
      }
    }
    drain_vm();
    // prefetch next layer's A weights + params
    if (l + 1 < NLAYER) {
      if (hasA) {
        const float* W = (matA == 0 ? p.kw : matA == 1 ? p.vw : p.rw) +
                         (size_t)(l + 1) * E * E + (size_t)rmA * E;
        pf_row4k(W, wA, lane);
      }
      ln1w = p.ln1_w[(l + 1) * E + tid]; ln1b = p.ln1_b[(l + 1) * E + tid];
      tmk_ = p.tmk[(l + 1) * E + tid];
      tmv_ = p.tmv[(l + 1) * E + tid];
      tmr_ = p.tmr[(l + 1) * E + tid];
      attx = p.st[(size_t)5 * (l + 1) * E + 1 * E + tid];
    }
    gbar(bar, ++gen * NB);

    s_x[tid] = ldg1(&ws_x[tid]);
    __syncthreads();
  }

  // ================ Head: LN_out + V x E matvec ================
  {
    float xv_ = s_x[tid];
    float m = block_sum(xv_, s_red) * (1.f / E);
    float d = xv_ - m;
    float var = block_sum(d * d, s_red) * (1.f / E);
    s_xk[tid] = d / sqrtf(var + LN_EPS) * p.lnow[tid] + p.lnob[tid];
  }
  __syncthreads();
  for (int row = gw; row < V; row += NWAVE) {
    const float* Wr = p.headw + (size_t)row * E;
    float dres = dot1024(Wr, s_xk, lane);
    if (lane == 0) p.out[row] = dres;
  }
}

extern "C" void kernel_launch(void* const* d_in, const int* in_sizes, int n_in,
                              void* d_out, int out_size, void* d_ws, size_t ws_size,
                              hipStream_t stream) {
  Params p;
  p.emb   = (const float*)d_in[0];
  p.ln0_w = (const float*)d_in[1];
  p.ln0_b = (const float*)d_in[2];
  p.ln1_w = (const float*)d_in[3];
  p.ln1_b = (const float*)d_in[4];
  p.tmk   = (const float*)d_in[5];
  p.tmv   = (const float*)d_in[6];
  p.tmr   = (const float*)d_in[7];
  p.tf    = (const float*)d_in[8];
  p.td    = (const float*)d_in[9];
  p.kw    = (const float*)d_in[10];
  p.vw    = (const float*)d_in[11];
  p.rw    = (const float*)d_in[12];
  p.ow    = (const float*)d_in[13];
  p.ln2_w = (const float*)d_in[14];
  p.ln2_b = (const float*)d_in[15];
  p.ftmk  = (const float*)d_in[16];
  p.ftmr  = (const float*)d_in[17];
  p.fkw   = (const float*)d_in[18];
  p.fvw   = (const float*)d_in[19];
  p.frw   = (const float*)d_in[20];
  p.lnow  = (const float*)d_in[21];
  p.lnob  = (const float*)d_in[22];
  p.headw = (const float*)d_in[23];
  if (in_sizes[24] == 1) {
    p.tok = (const int*)d_in[24];
    p.st  = (const float*)d_in[25];
  } else {
    p.st  = (const float*)d_in[24];
    p.tok = (const int*)d_in[25];
  }
  p.out   = (float*)d_out;
  p.ws    = (float*)d_ws;

  // zero the barrier counter region deterministically every call (graph node)
  hipMemsetAsync(d_ws, 0, 16384, stream);

  void* args[] = { &p };
  hipLaunchCooperativeKernel((const void*)rwkv_kernel, dim3(NB), dim3(NT),
                             args, SMEM_FLOATS * sizeof(float), stream);
}

// Round 7
// 672.135 us; speedup vs baseline: 1.7468x; 1.6522x over previous
//
#include <hip/hip_runtime.h>

#define E 1024
#define H 4096
#define NLAYER 24
#define V 50277
#define NB 256
#define NT 1024
#define NWAVE ((NB * NT) / 64)   // 4096 waves
#define LN_EPS 1e-5f

typedef unsigned long long u64;

// ---- LDS float offsets (dynamic shared) ----
#define WBUF   0        // 16 waves x 1024 floats (64 KB) wave-private weights
#define WFRW   16384    // 4 x 1024 floats (16 KB) frw rows for waves 0..3
#define OFF_X    20480
#define OFF_XK   21504
#define OFF_XV   22528
#define OFF_XR   23552
#define OFF_WKV  24576
#define OFF_SX   25600
#define OFF_FXK  26624
#define OFF_FXR  27648
#define OFF_FK   28672  // 4096
#define OFF_RED  32768  // 16
#define OFF_PART 32784  // 16
#define OFF_FR   32800  // 4
#define SMEM_FLOATS 32804

struct Params {
  const float* emb;   const float* ln0_w; const float* ln0_b;
  const float* ln1_w; const float* ln1_b;
  const float* tmk;   const float* tmv;   const float* tmr;
  const float* tf;    const float* td;
  const float* kw;    const float* vw;    const float* rw;  const float* ow;
  const float* ln2_w; const float* ln2_b;
  const float* ftmk;  const float* ftmr;
  const float* fkw;   const float* fvw;   const float* frw;
  const float* lnow;  const float* lnob;  const float* headw;
  const float* st;    const int* tok;
  float* out; float* ws;
};

// ---- tagged 8-byte dataflow handoff (relaxed agent scope; tag+value atomic) ----
__device__ __forceinline__ void stg_tag(u64* p, float v, unsigned tag) {
  u64 w = ((u64)__float_as_uint(v) << 32) | (u64)tag;
  __hip_atomic_store(p, w, __ATOMIC_RELAXED, __HIP_MEMORY_SCOPE_AGENT);
}
__device__ __forceinline__ u64 ld_tag(const u64* p) {
  return __hip_atomic_load(p, __ATOMIC_RELAXED, __HIP_MEMORY_SCOPE_AGENT);
}
__device__ __forceinline__ float poll_tag(const u64* p, unsigned tag) {
  u64 w = ld_tag(p);
  while ((unsigned)w != tag) { __builtin_amdgcn_s_sleep(1); w = ld_tag(p); }
  return __uint_as_float((unsigned)(w >> 32));
}
__device__ __forceinline__ void poll3(const u64* a, const u64* b, const u64* c,
                                      unsigned tag, float& x, float& y, float& z) {
  u64 wa = ld_tag(a), wb = ld_tag(b), wc = ld_tag(c);   // 3 loads in flight
  while ((unsigned)wa != tag) { __builtin_amdgcn_s_sleep(1); wa = ld_tag(a); }
  while ((unsigned)wb != tag) { __builtin_amdgcn_s_sleep(1); wb = ld_tag(b); }
  while ((unsigned)wc != tag) { __builtin_amdgcn_s_sleep(1); wc = ld_tag(c); }
  x = __uint_as_float((unsigned)(wa >> 32));
  y = __uint_as_float((unsigned)(wb >> 32));
  z = __uint_as_float((unsigned)(wc >> 32));
}

// wait for this wave's global_load_lds DMAs (and any loads) to complete
__device__ __forceinline__ void wait_pf() {
  asm volatile("s_waitcnt vmcnt(0)" ::: "memory");
}

// zero-VGPR global->LDS DMA: 64 lanes x 16 B = 1 KB per call.
__device__ __forceinline__ void gload_lds16(const float* g, float* l) {
  __builtin_amdgcn_global_load_lds(
      (const __attribute__((address_space(1))) unsigned int*)(g),
      (__attribute__((address_space(3))) unsigned int*)(l), 16, 0, 0);
}
__device__ __forceinline__ void pf_row4k(const float* row, float* dst, int lane) {
#pragma unroll
  for (int c = 0; c < 4; ++c)
    gload_lds16(row + c * 256 + lane * 4, dst + c * 256);
}

__device__ __forceinline__ float warp_sum(float v) {
#pragma unroll
  for (int off = 32; off; off >>= 1) v += __shfl_down(v, off);
  return v;
}

__device__ float block_sum(float v, float* red) {
  v = warp_sum(v);
  const int wid = threadIdx.x >> 6, lane = threadIdx.x & 63;
  if (lane == 0) red[wid] = v;
  __syncthreads();
  float s = (threadIdx.x < 16) ? red[threadIdx.x] : 0.f;
  if (wid == 0) {
#pragma unroll
    for (int off = 8; off; off >>= 1) s += __shfl_down(s, off);
    if (lane == 0) red[0] = s;
  }
  __syncthreads();
  float r = red[0];
  __syncthreads();
  return r;
}

__device__ __forceinline__ float dot4(float4 a, float4 b) {
  return a.x * b.x + a.y * b.y + a.z * b.z + a.w * b.w;
}

__device__ __forceinline__ float dotlds(const float* wrow, const float* vec, int lane) {
  const float4* w4 = (const float4*)wrow;
  const float4* v4 = (const float4*)vec;
  float acc = 0.f;
#pragma unroll
  for (int p = 0; p < 4; ++p)
    acc += dot4(w4[lane + p * 64], v4[lane + p * 64]);
  return warp_sum(acc);
}

__device__ __forceinline__ float dot1024(const float* __restrict__ Wrow,
                                         const float* vec, int lane) {
  const float4* W4 = (const float4*)Wrow;
  const float4* v4 = (const float4*)vec;
  float acc = 0.f;
#pragma unroll
  for (int p = 0; p < 4; ++p)
    acc += dot4(W4[lane + p * 64], v4[lane + p * 64]);
  return warp_sum(acc);
}

__global__ __launch_bounds__(NT, 1) void rwkv_kernel(Params p) {
  const int tid = threadIdx.x, bid = blockIdx.x;
  const int lane = tid & 63, wid = tid >> 6;
  const int gw = bid * 16 + wid;          // 0..4095

  extern __shared__ float smem[];
  float* wbuf  = smem + WBUF;
  float* wfrw  = smem + WFRW;
  float* s_x   = smem + OFF_X;
  float* s_xk  = smem + OFF_XK;
  float* s_xv  = smem + OFF_XV;
  float* s_xr  = smem + OFF_XR;
  float* s_wkv = smem + OFF_WKV;
  float* s_sx  = smem + OFF_SX;
  float* s_fxk = smem + OFF_FXK;
  float* s_fxr = smem + OFF_FXR;
  float* s_fk  = smem + OFF_FK;
  float* s_red = smem + OFF_RED;
  float* s_part= smem + OFF_PART;
  float* s_fr  = smem + OFF_FR;

  // tagged dataflow arrays in ws (all u64 {tag, value}), parity double-buffered
  u64* tws = (u64*)p.ws;
  u64* tk  = tws;             // [2][E]
  u64* tv  = tws + 2 * E;     // [2][E]
  u64* tr  = tws + 4 * E;     // [2][E]
  u64* tsx = tws + 6 * E;     // [2][E]
  u64* tx  = tws + 8 * E;     // [2][E]
  u64* tfk = tws + 10 * E;    // [2][H]

  float* out_st = p.out + V;
  const int token = p.tok[0];

  // wave->row mappings (constant across layers)
  const bool hasA = wid < 12;             // 256 blocks x 12 waves = 3072 rows
  const int rA = bid * 12 + wid;          // valid when hasA
  const int matA = rA >> 10, rmA = rA & (E - 1);
  const int kcB = wid & 3, rowB = bid * 4 + (wid >> 2);
  const int kcD = wid & 3, rowD = bid * 4 + (wid >> 2);

  float* wA = wbuf + wid * 1024;          // wave-private 4 KB
  float* wF = wfrw + wid * 1024;          // only wid<4

  // x = LN0(emb[token]) -- redundant per block
  {
    float v = p.emb[(size_t)token * E + tid];
    float m = block_sum(v, s_red) * (1.f / E);
    float d = v - m;
    float var = block_sum(d * d, s_red) * (1.f / E);
    s_x[tid] = d / sqrtf(var + LN_EPS) * p.ln0_w[tid] + p.ln0_b[tid];
  }
  __syncthreads();

  for (int l = 0; l < NLAYER; ++l) {
    const float* stl = p.st + (size_t)5 * l * E;
    float* ostl = out_st + (size_t)5 * l * E;
    const int par = l & 1;
    const unsigned tg = (unsigned)(l + 1);

    // ================ Phase A: LN1 + mix + k/v/r matvec slice ================
    if (hasA) {
      const float* W = (matA == 0 ? p.kw : matA == 1 ? p.vw : p.rw) +
                       (size_t)l * E * E + (size_t)rmA * E;
      pf_row4k(W, wA, lane);              // DMA overlaps the poll below
    }
    if (l > 0) {
      s_x[tid] = poll_tag(&tx[par * E + tid], (unsigned)l);
    }
    {
      float xv_ = s_x[tid];
      float m = block_sum(xv_, s_red) * (1.f / E);
      float d = xv_ - m;
      float var = block_sum(d * d, s_red) * (1.f / E);
      float xn = d / sqrtf(var + LN_EPS) * p.ln1_w[l * E + tid] + p.ln1_b[l * E + tid];
      float ax = stl[1 * E + tid];
      float tk_ = p.tmk[l * E + tid], tv_ = p.tmv[l * E + tid], tr_ = p.tmr[l * E + tid];
      s_xk[tid] = xn * tk_ + ax * (1.f - tk_);
      s_xv[tid] = xn * tv_ + ax * (1.f - tv_);
      s_xr[tid] = xn * tr_ + ax * (1.f - tr_);
      if (bid == 0) ostl[1 * E + tid] = xn;       // new att_x
    }
    __syncthreads();
    wait_pf();
    if (hasA) {
      const float* vec = (matA == 0) ? s_xk : (matA == 1) ? s_xv : s_xr;
      float dres = dotlds(wA, vec, lane);
      if (lane == 0) {
        u64* dst = (matA == 0 ? tk : matA == 1 ? tv : tr) + par * E + rmA;
        float val = (matA == 2) ? 1.f / (1.f + expf(-dres)) : dres;
        stg_tag(dst, val, tg);
      }
    }

    // ================ Phase B: WKV + ow matvec ================
    gload_lds16(p.ow + (size_t)l * E * E + (size_t)rowB * E + kcB * 256 + lane * 4, wA);
    {
      float kk, vv, rr;
      poll3(&tk[par * E + tid], &tv[par * E + tid], &tr[par * E + tid], tg, kk, vv, rr);
      float aav = stl[2 * E + tid], bbv = stl[3 * E + tid], ppv = stl[4 * E + tid];
      float tfv = p.tf[l * E + tid], tdv = p.td[l * E + tid];
      float wwv = tfv + kk;
      float pm = fmaxf(ppv, wwv);
      float e1 = expf(ppv - pm), e2 = expf(wwv - pm);
      float a = e1 * aav + e2 * vv, b = e1 * bbv + e2;
      s_wkv[tid] = rr * a / b;
      float ww2 = ppv + tdv;
      float p2 = fmaxf(ww2, kk);
      float f1 = expf(ww2 - p2), f2 = expf(kk - p2);
      if (bid == 0) {
        ostl[2 * E + tid] = f1 * aav + f2 * vv;    // naa
        ostl[3 * E + tid] = f1 * bbv + f2;         // nbb
        ostl[4 * E + tid] = p2;                    // npp
      }
    }
    __syncthreads();
    wait_pf();
    {
      const float4* v4 = (const float4*)(s_wkv + kcB * 256);
      const float4* w4 = (const float4*)wA;
      float acc = warp_sum(dot4(w4[lane], v4[lane]));
      if (lane == 0) s_part[wid] = acc;
    }
    __syncthreads();
    if (tid < 4) {
      int r2 = bid * 4 + tid;
      float dsum = s_part[tid * 4] + s_part[tid * 4 + 1] +
                   s_part[tid * 4 + 2] + s_part[tid * 4 + 3];
      stg_tag(&tsx[par * E + r2], s_x[r2] + dsum, tg);
    }

    // ================ Phase C: LN2 + mix + fkw/frw matvecs ================
    pf_row4k(p.fkw + (size_t)l * H * E + (size_t)gw * E, wA, lane);
    if (wid < 4)
      pf_row4k(p.frw + (size_t)l * E * E + (size_t)(bid * 4 + wid) * E, wF, lane);
    {
      float sxv = poll_tag(&tsx[par * E + tid], tg);
      s_sx[tid] = sxv;
      float m = block_sum(sxv, s_red) * (1.f / E);
      float d = sxv - m;
      float var = block_sum(d * d, s_red) * (1.f / E);
      float xn2 = d / sqrtf(var + LN_EPS) * p.ln2_w[l * E + tid] + p.ln2_b[l * E + tid];
      float fx = stl[0 * E + tid];
      float ftk = p.ftmk[l * E + tid], ftr = p.ftmr[l * E + tid];
      s_fxk[tid] = xn2 * ftk + fx * (1.f - ftk);
      s_fxr[tid] = xn2 * ftr + fx * (1.f - ftr);
      if (bid == 0) ostl[0 * E + tid] = xn2;       // new ffn_x
    }
    __syncthreads();
    wait_pf();
    {
      float dres = dotlds(wA, s_fxk, lane);
      if (lane == 0) { float t = fmaxf(dres, 0.f); stg_tag(&tfk[par * H + gw], t * t, tg); }
      if (wid < 4) {
        float dr2 = dotlds(wF, s_fxr, lane);
        if (lane == 0) s_fr[wid] = 1.f / (1.f + expf(-dr2));   // block-local
      }
    }

    // ================ Phase D: fvw matvec + residual ================
    pf_row4k(p.fvw + (size_t)l * E * H + (size_t)rowD * H + kcD * 1024, wA, lane);
#pragma unroll
    for (int i = 0; i < 4; ++i)
      s_fk[tid + i * NT] = poll_tag(&tfk[par * H + tid + i * NT], tg);
    __syncthreads();
    wait_pf();
    {
      const float4* v4 = (const float4*)(s_fk + kcD * 1024);
      const float4* w4 = (const float4*)wA;
      float acc = 0.f;
#pragma unroll
      for (int pc = 0; pc < 4; ++pc)
        acc += dot4(w4[lane + pc * 64], v4[lane + pc * 64]);
      acc = warp_sum(acc);
      if (lane == 0) s_part[wid] = acc;
    }
    __syncthreads();
    if (tid < 4) {
      int r2 = bid * 4 + tid;
      float dsum = s_part[tid * 4] + s_part[tid * 4 + 1] +
                   s_part[tid * 4 + 2] + s_part[tid * 4 + 3];
      stg_tag(&tx[((l + 1) & 1) * E + r2], s_sx[r2] + s_fr[tid] * dsum, tg);
    }
  }

  // ================ Head: LN_out + V x E matvec ================
  {
    float xv_ = poll_tag(&tx[(NLAYER & 1) * E + tid], (unsigned)NLAYER);
    float m = block_sum(xv_, s_red) * (1.f / E);
    float d = xv_ - m;
    float var = block_sum(d * d, s_red) * (1.f / E);
    s_xk[tid] = d / sqrtf(var + LN_EPS) * p.lnow[tid] + p.lnob[tid];
  }
  __syncthreads();
  for (int row = gw; row < V; row += NWAVE) {
    const float* Wr = p.headw + (size_t)row * E;
    float dres = dot1024(Wr, s_xk, lane);
    if (lane == 0) p.out[row] = dres;
  }
}

extern "C" void kernel_launch(void* const* d_in, const int* in_sizes, int n_in,
                              void* d_out, int out_size, void* d_ws, size_t ws_size,
                              hipStream_t stream) {
  Params p;
  p.emb   = (const float*)d_in[0];
  p.ln0_w = (const float*)d_in[1];
  p.ln0_b = (const float*)d_in[2];
  p.ln1_w = (const float*)d_in[3];
  p.ln1_b = (const float*)d_in[4];
  p.tmk   = (const float*)d_in[5];
  p.tmv   = (const float*)d_in[6];
  p.tmr   = (const float*)d_in[7];
  p.tf    = (const float*)d_in[8];
  p.td    = (const float*)d_in[9];
  p.kw    = (const float*)d_in[10];
  p.vw    = (const float*)d_in[11];
  p.rw    = (const float*)d_in[12];
  p.ow    = (const float*)d_in[13];
  p.ln2_w = (const float*)d_in[14];
  p.ln2_b = (const float*)d_in[15];
  p.ftmk  = (const float*)d_in[16];
  p.ftmr  = (const float*)d_in[17];
  p.fkw   = (const float*)d_in[18];
  p.fvw   = (const float*)d_in[19];
  p.frw   = (const float*)d_in[20];
  p.lnow  = (const float*)d_in[21];
  p.lnob  = (const float*)d_in[22];
  p.headw = (const float*)d_in[23];
  if (in_sizes[24] == 1) {
    p.tok = (const int*)d_in[24];
    p.st  = (const float*)d_in[25];
  } else {
    p.st  = (const float*)d_in[24];
    p.tok = (const int*)d_in[25];
  }
  p.out   = (float*)d_out;
  p.ws    = (float*)d_ws;

  // zero ALL tag words each launch (graph node): (10E + 2H) u64 = 147456 B
  hipMemsetAsync(d_ws, 0, (10 * E + 2 * H) * sizeof(unsigned long long), stream);

  void* args[] = { &p };
  hipLaunchCooperativeKernel((const void*)rwkv_kernel, dim3(NB), dim3(NT),
                             args, SMEM_FLOATS * sizeof(float), stream);
}